// Round 1
// baseline (108.847 us; speedup 1.0000x reference)
//
#include <hip/hip_runtime.h>

// Tiny MLP 2->15->15->15->1 (SiLU x3, sigmoid), N=2^21 rows, fp32 in/out.
//
// Round-16: single-dispatch DIRECT MFMA compute (no table, no workspace).
// Rationale: rocprof shows the 95 us total is dominated by two ~43.5 us
// harness re-poison fills of the 256 MiB workspace; our kernels are the
// residual ~8 us. Direct compute removes K1 (table build), its scatter
// stores, the second launch, and K2's random 8 B gathers.
//
// Per wave: 64 samples as 4 independent MFMA groups of 16.
//   B/D layout chain (proven in the r11 table builder): for
//   mfma_f32_16x16x16f16, D(col=lane&15, row=quad*4+i) == B(n=lane&15,
//   k=quad*4+i), so layer2/3/4 chain in-register with zero shuffles.
//   Lane 'col' owns samples base+col*4+{0..3} (g = group), so the final
//   4 sigmoids form one coalesced float4 store from lanes 0-15.
// Layer1 (2->15) is VALU fp32 (2 fma/neuron), layers 2-4 are f16 MFMA
// with fp32 accumulate. Error budget: same f16-fragment error as the
// old table NODES, minus the bilinear-interp error => absmax should drop.

using half4   = __attribute__((ext_vector_type(4))) _Float16;
using half2v  = __attribute__((ext_vector_type(2))) _Float16;
using fp16x2  = __attribute__((ext_vector_type(2))) __fp16;
using floatx4 = __attribute__((ext_vector_type(4))) float;
using v2f     = __attribute__((ext_vector_type(2))) float;

__device__ __forceinline__ v2f sigmoid2_exp(v2f x) {
    v2f den;
    den[0] = 1.0f + __expf(-x[0]);
    den[1] = 1.0f + __expf(-x[1]);
    const float r = __builtin_amdgcn_rcpf(den[0] * den[1]);
    return (v2f){den[1] * r, den[0] * r};
}

__device__ __forceinline__ half2v silu2h_exp(v2f x) {
    v2f s = x * sigmoid2_exp(x);
    fp16x2 p = __builtin_amdgcn_cvt_pkrtz(s[0], s[1]);
    return __builtin_bit_cast(half2v, p);
}

__global__ __launch_bounds__(256) void mlp_direct(
    const float* __restrict__ x,
    const float* __restrict__ W1, const float* __restrict__ b1,
    const float* __restrict__ W2, const float* __restrict__ b2,
    const float* __restrict__ W3, const float* __restrict__ b3,
    const float* __restrict__ W4, const float* __restrict__ b4,
    float* __restrict__ out, int N)
{
    const int lane = threadIdx.x & 63;
    const int col  = lane & 15;
    const int quad = lane >> 4;

    // ---- weight preamble (identical convention to the r11 table builder) ----
    // A[m][k] = W[k][m]; lane holds k = quad*4+i for m = col.
    half4 A2, A3, A4;
    v2f w10p[2], w11p[2], vb1p[2], vb2p[2], vb3p[2];
    #pragma unroll
    for (int i = 0; i < 4; ++i) {
        const int k    = quad * 4 + i;
        const int m    = col;
        const bool kin = (k < 15);
        A2[i] = (_Float16)((kin && m < 15) ? W2[k * 15 + m] : 0.0f);
        A3[i] = (_Float16)((kin && m < 15) ? W3[k * 15 + m] : 0.0f);
        A4[i] = (_Float16)((kin && m == 0) ? W4[k]          : 0.0f);
        w10p[i >> 1][i & 1] = kin ? W1[k]      : 0.0f;   // W1[0][k]
        w11p[i >> 1][i & 1] = kin ? W1[15 + k] : 0.0f;   // W1[1][k]
        vb1p[i >> 1][i & 1] = kin ? b1[k]      : 0.0f;
        vb2p[i >> 1][i & 1] = kin ? b2[k]      : 0.0f;   // bias for D row m=k
        vb3p[i >> 1][i & 1] = kin ? b3[k]      : 0.0f;
    }
    const float b4s = b4[0];
    const floatx4 zero = {0.f, 0.f, 0.f, 0.f};

    const int gwave = (blockIdx.x * 256 + threadIdx.x) >> 6;
    const int nwave = (gridDim.x * 256) >> 6;
    const int niter = N >> 6;                  // 64 samples per wave-iter

    const float4* x4   = reinterpret_cast<const float4*>(x);
    float4*       out4 = reinterpret_cast<float4*>(out);

    for (int w = gwave; w < niter; w += nwave) {
        const int base = w << 6;               // first sample of this wave-iter

        // lane 'col' owns samples base + col*4 + {0,1,2,3}; 32 B contiguous.
        // (4-way address duplication across quads -> coalescer merges.)
        const float4 xA = x4[(base >> 1) + col * 2];      // {x0,y0,x1,y1}
        const float4 xB = x4[(base >> 1) + col * 2 + 1];  // {x2,y2,x3,y3}
        const float xg[4] = {xA.x, xA.z, xB.x, xB.z};
        const float yg[4] = {xA.y, xA.w, xB.y, xB.w};

        // ---- layer 1 (VALU fp32) -> f16 B fragments, k = quad*4+i ----
        half4 B[4];
        #pragma unroll
        for (int g = 0; g < 4; ++g) {
            #pragma unroll
            for (int j = 0; j < 2; ++j) {
                v2f a = w10p[j] * xg[g] + (w11p[j] * yg[g] + vb1p[j]);
                half2v p = silu2h_exp(a);
                B[g][2 * j]     = p[0];
                B[g][2 * j + 1] = p[1];
            }
        }

        // ---- layer 2 ----
        floatx4 d[4];
        #pragma unroll
        for (int g = 0; g < 4; ++g)
            d[g] = __builtin_amdgcn_mfma_f32_16x16x16f16(A2, B[g], zero, 0, 0, 0);
        #pragma unroll
        for (int g = 0; g < 4; ++g) {
            #pragma unroll
            for (int j = 0; j < 2; ++j) {
                v2f t = (v2f){d[g][2 * j], d[g][2 * j + 1]} + vb2p[j];
                half2v p = silu2h_exp(t);
                B[g][2 * j]     = p[0];
                B[g][2 * j + 1] = p[1];
            }
        }

        // ---- layer 3 ----
        #pragma unroll
        for (int g = 0; g < 4; ++g)
            d[g] = __builtin_amdgcn_mfma_f32_16x16x16f16(A3, B[g], zero, 0, 0, 0);
        #pragma unroll
        for (int g = 0; g < 4; ++g) {
            #pragma unroll
            for (int j = 0; j < 2; ++j) {
                v2f t = (v2f){d[g][2 * j], d[g][2 * j + 1]} + vb3p[j];
                half2v p = silu2h_exp(t);
                B[g][2 * j]     = p[0];
                B[g][2 * j + 1] = p[1];
            }
        }

        // ---- layer 4 (m=0 only) ----
        #pragma unroll
        for (int g = 0; g < 4; ++g)
            d[g] = __builtin_amdgcn_mfma_f32_16x16x16f16(A4, B[g], zero, 0, 0, 0);

        // logit for sample (col, g) sits in d[g][0] on quad 0 (row m=0).
        if (quad == 0) {
            const v2f s01 = sigmoid2_exp((v2f){d[0][0] + b4s, d[1][0] + b4s});
            const v2f s23 = sigmoid2_exp((v2f){d[2][0] + b4s, d[3][0] + b4s});
            out4[(base >> 2) + col] = (float4){s01[0], s01[1], s23[0], s23[1]};
        }
    }
}

extern "C" void kernel_launch(void* const* d_in, const int* in_sizes, int n_in,
                              void* d_out, int out_size, void* d_ws, size_t ws_size,
                              hipStream_t stream) {
    const float* x  = (const float*)d_in[0];
    const float* W1 = (const float*)d_in[1];
    const float* b1 = (const float*)d_in[2];
    const float* W2 = (const float*)d_in[3];
    const float* b2 = (const float*)d_in[4];
    const float* W3 = (const float*)d_in[5];
    const float* b3 = (const float*)d_in[6];
    const float* W4 = (const float*)d_in[7];
    const float* b4 = (const float*)d_in[8];
    float* out = (float*)d_out;

    const int N = in_sizes[0] / 2;             // 2,097,152 rows

    // 4096 blocks x 256 threads = 16384 waves; 32768 wave-iters total
    // -> 2 iterations/wave (amortizes weight preamble, fine-grained tail).
    mlp_direct<<<4096, 256, 0, stream>>>(x, W1, b1, W2, b2, W3, b3, W4, b4,
                                         out, N);
}